// Round 12
// baseline (82.591 us; speedup 1.0000x reference)
//
#include <hip/hip_runtime.h>
#include <hip/hip_bf16.h>

#define B_SZ 4096
#define N_SZ 8192
#define D_SZ 128
#define NRB 64          // 128-row/col blocks

constexpr float TEMP = 0.5f;
constexpr float EPS = 1e-8f;
// exp(dot/TEMP) = exp2(dot * log2(e)/TEMP); sqrt of the scale folded into
// BOTH normalized vectors so the MFMA accumulator is directly the exp2 arg.
constexpr float SQS = 1.6986436006556212f;  // sqrt(log2(e)/TEMP)

typedef short short8 __attribute__((ext_vector_type(8)));
typedef float f32x16 __attribute__((ext_vector_type(16)));

// Tiled pn layout (bf16): byte addr of element (row r, col d) =
//   (r>>5)*8192 + (d>>3)*512 + (r&31)*16 + (d&7)*2

// ---------------------------------------------------------------------------
// Kernel A: unchanged from r7.
// ---------------------------------------------------------------------------
__global__ void norm_pos_kernel(const float* __restrict__ z_i,
                                const float* __restrict__ z_j,
                                unsigned int* __restrict__ pn_u32,
                                float* __restrict__ posbuf,
                                float* __restrict__ selfexp,
                                float* __restrict__ out) {
    __shared__ float sp[4];
    int wid = threadIdx.x >> 6;
    int lane = threadIdx.x & 63;
    int r = blockIdx.x * 4 + wid;                 // [0, B)
    if (blockIdx.x == 0 && threadIdx.x == 0) out[0] = 0.0f;
    float2 vi = *reinterpret_cast<const float2*>(z_i + (size_t)r * D_SZ + lane * 2);
    float2 vj = *reinterpret_cast<const float2*>(z_j + (size_t)r * D_SZ + lane * 2);
    float ssi = vi.x * vi.x + vi.y * vi.y;
    float ssj = vj.x * vj.x + vj.y * vj.y;
    float dot = vi.x * vj.x + vi.y * vj.y;
#pragma unroll
    for (int m = 32; m >= 1; m >>= 1) {
        ssi += __shfl_xor(ssi, m, 64);
        ssj += __shfl_xor(ssj, m, 64);
        dot += __shfl_xor(dot, m, 64);
    }
    float ni = fmaxf(sqrtf(ssi), EPS);
    float nj = fmaxf(sqrtf(ssj), EPS);
    float si = SQS / ni, sj = SQS / nj;
    union { unsigned int u32; __hip_bfloat16 h[2]; } pki, pkj;
    pki.h[0] = __float2bfloat16(vi.x * si);
    pki.h[1] = __float2bfloat16(vi.y * si);
    pkj.h[0] = __float2bfloat16(vj.x * sj);
    pkj.h[1] = __float2bfloat16(vj.y * sj);
    int u = ((r >> 5) * 2048) + ((lane >> 2) * 128) + ((r & 31) * 4) + (lane & 3);
    pn_u32[u] = pki.u32;
    int r2 = r + B_SZ;
    int u2 = ((r2 >> 5) * 2048) + ((lane >> 2) * 128) + ((r2 & 31) * 4) + (lane & 3);
    pn_u32[u2] = pkj.u32;
    float bx = __bfloat162float(pki.h[0]), by = __bfloat162float(pki.h[1]);
    float cx = __bfloat162float(pkj.h[0]), cy = __bfloat162float(pkj.h[1]);
    float sdi = bx * bx + by * by;
    float sdj = cx * cx + cy * cy;
#pragma unroll
    for (int m = 32; m >= 1; m >>= 1) {
        sdi += __shfl_xor(sdi, m, 64);
        sdj += __shfl_xor(sdj, m, 64);
    }
    if (lane == 0) {
        selfexp[r] = __builtin_amdgcn_exp2f(sdi);
        selfexp[r2] = __builtin_amdgcn_exp2f(sdj);
        sp[wid] = -dot / (ni * nj * TEMP) / (float)B_SZ;
    }
    __syncthreads();
    if (threadIdx.x == 0)
        posbuf[blockIdx.x] = sp[0] + sp[1] + sp[2] + sp[3];
}

// ---------------------------------------------------------------------------
// Kernel B (SYMMETRIC, wrapped-window, r7 skeleton): 512 blocks = 64 row-
// blocks x 8 strips; strip s of row-block bx covers col-blocks
// j = (bx + 4s + m) mod 64, m=0..3 -> 16 globally-contiguous col-tiles
// ct(t) = (4*(bx+4s)+t) & 255. Strip 7 of bx<32 extends to o=32 (NT=20).
// Coverage of unordered pair {i,j}: o=(j-i)%64: o=0 diag (rowsum only,
// self removed via selfexp); o in [1,31] from side i (rowsum + mirror
// colsum); o=32 from i<32. Exactly once each.
//   rowsum of strip s -> partialR[s][rows of bx]       (8 slots, no zeroing)
//   colsum of tile t  -> cs[t] REGISTER, flushed in epilogue to
//                        partialC[2*bx+wid][col], written exactly once.
// Hot loop identical to r7: stage + compute + barrier, no global stores.
// Tile loop FULLY UNROLLED so cs[] indices are static (rule #20).
// __launch_bounds__(128,2): (128,4) spilled in r9.
// C/D layout: col=lane&31, row=(reg&3)+8*(reg>>2)+4*(lane>>5).
// ---------------------------------------------------------------------------
__global__ __launch_bounds__(128, 2)
void simexp_kernel(const char* __restrict__ p,
                   float* __restrict__ partialR,
                   float* __restrict__ partialC) {
    __shared__ char bufA[8192];
    __shared__ char bufB[8192];
    int wid = threadIdx.x >> 6;
    int lane = threadIdx.x & 63;
    int half = lane >> 5, lc = lane & 31;

    int swz = (blockIdx.x & 7) * 64 + (blockIdx.x >> 3);  // 512 = 8*64
    int bx = swz >> 3;            // row-block [0,64)
    int s = swz & 7;              // strip [0,8)
    int ctBase = (4 * (bx + 4 * s)) & 255;
    bool diag = (s == 0);         // tiles 0..3 are the diagonal block
    bool heavy = (s == 7) && (bx < 32);   // +4 tiles for o=32 band

    int rt0 = bx * 4 + wid * 2;   // wave's row-tiles (32-row units)

    const char* afrag = p + (size_t)rt0 * 8192 + half * 512 + lc * 16;
    short8 a0[8], a1[8];
#pragma unroll
    for (int kc = 0; kc < 8; ++kc) {
        a0[kc] = *reinterpret_cast<const short8*>(afrag + kc * 1024);
        a1[kc] = *reinterpret_cast<const short8*>(afrag + 8192 + kc * 1024);
    }

    float rs0[16], rs1[16];
#pragma unroll
    for (int q = 0; q < 16; ++q) { rs0[q] = 0.0f; rs1[q] = 0.0f; }
    float cs[20];

    auto stage = [&](char* buf, int ct) {
#pragma unroll
        for (int sg = 0; sg < 4; ++sg) {
            int seg = wid * 4 + sg;
            const char* g = p + (size_t)ct * 8192 + seg * 1024 + lane * 16;
            __builtin_amdgcn_global_load_lds(
                (const __attribute__((address_space(1))) unsigned int*)g,
                (__attribute__((address_space(3))) unsigned int*)(buf + seg * 1024),
                16, 0, 0);
        }
    };

    auto compute = [&](const char* buf, bool doCol, float& csOut) {
        const char* bb = buf + half * 512 + lc * 16;
        short8 bfrag[8];
#pragma unroll
        for (int kc = 0; kc < 8; ++kc)
            bfrag[kc] = *reinterpret_cast<const short8*>(bb + kc * 1024);
        f32x16 acc0 = {}, acc1 = {};
#pragma unroll
        for (int kc = 0; kc < 8; ++kc) {
            acc0 = __builtin_amdgcn_mfma_f32_32x32x16_bf16(a0[kc], bfrag[kc], acc0, 0, 0, 0);
            acc1 = __builtin_amdgcn_mfma_f32_32x32x16_bf16(a1[kc], bfrag[kc], acc1, 0, 0, 0);
        }
        float c01 = 0.0f;
#pragma unroll
        for (int q = 0; q < 16; ++q) {
            float e0 = __builtin_amdgcn_exp2f(acc0[q]);
            float e1 = __builtin_amdgcn_exp2f(acc1[q]);
            rs0[q] += e0;
            rs1[q] += e1;
            c01 += e0 + e1;
        }
        if (doCol) {
            c01 += __shfl_xor(c01, 32, 64);  // combine row-halves: 64-row colsum
            csOut = c01;
        }
    };

// tile T: even T computes bufA, odd T computes bufB; stage goes to the other
#define TILE(T, STAGE_NEXT)                                                   \
    {                                                                         \
        if (STAGE_NEXT) stage(((T) & 1) ? bufA : bufB, (ctBase + (T) + 1) & 255); \
        compute(((T) & 1) ? bufB : bufA, !diag || (T) >= 4, cs[T]);           \
        __syncthreads();                                                      \
    }

    stage(bufA, ctBase);
    __syncthreads();
    TILE(0, true)  TILE(1, true)  TILE(2, true)  TILE(3, true)
    TILE(4, true)  TILE(5, true)  TILE(6, true)  TILE(7, true)
    TILE(8, true)  TILE(9, true)  TILE(10, true) TILE(11, true)
    TILE(12, true) TILE(13, true) TILE(14, true) TILE(15, heavy)
    if (heavy) {
        TILE(16, true) TILE(17, true) TILE(18, true) TILE(19, false)
    }
#undef TILE

    // rowsum: reduce across the 32 column lanes, one flush per block
#pragma unroll
    for (int m = 1; m <= 16; m <<= 1) {
#pragma unroll
        for (int q = 0; q < 16; ++q) {
            rs0[q] += __shfl_xor(rs0[q], m, 64);
            rs1[q] += __shfl_xor(rs1[q], m, 64);
        }
    }
    if (lc == 0) {
        float* dst = partialR + (size_t)s * N_SZ;
#pragma unroll
        for (int q = 0; q < 16; ++q) {
            int lrow = (q & 3) + 8 * (q >> 2) + 4 * half;
            dst[rt0 * 32 + lrow] = rs0[q];
            dst[(rt0 + 1) * 32 + lrow] = rs1[q];
        }
    }

    // colsum flush: row (2*bx+wid), contiguous columns; exactly-once writes
    if (half == 0) {
        float* crow = partialC + (size_t)(2 * bx + wid) * N_SZ;
#define CSTORE(T) if (!diag || (T) >= 4) crow[(((ctBase + (T)) & 255) << 5) + lc] = cs[T];
        CSTORE(0)  CSTORE(1)  CSTORE(2)  CSTORE(3)
        CSTORE(4)  CSTORE(5)  CSTORE(6)  CSTORE(7)
        CSTORE(8)  CSTORE(9)  CSTORE(10) CSTORE(11)
        CSTORE(12) CSTORE(13) CSTORE(14) CSTORE(15)
        if (heavy) { CSTORE(16) CSTORE(17) CSTORE(18) CSTORE(19) }
#undef CSTORE
    }
}

// ---------------------------------------------------------------------------
// Kernel C: loss = sum(log(rowsum - selfexp))/2B + pos partials.
// Row r (bj=r>>7): 8 rowsum slots + colsum rows {2i,2i+1} for i at wrapped
// distance o in [1,31] (+ i=bj-32 if bj>=32). All slots written exactly once.
// ---------------------------------------------------------------------------
__global__ void lse_kernel(const float* __restrict__ partialR,
                           const float* __restrict__ partialC,
                           const float* __restrict__ selfexp,
                           const float* __restrict__ posbuf,
                           float* __restrict__ out) {
    int r = blockIdx.x * 64 + threadIdx.x;
    int bj = r >> 7;
    float ssum = 0.0f;
#pragma unroll
    for (int s = 0; s < 8; ++s) ssum += partialR[(size_t)s * N_SZ + r];
    for (int o = 1; o < 32; ++o) {
        int i = (bj - o) & 63;
        ssum += partialC[(size_t)(2 * i) * N_SZ + r] +
                partialC[(size_t)(2 * i + 1) * N_SZ + r];
    }
    if (bj >= 32) {
        int i = bj - 32;
        ssum += partialC[(size_t)(2 * i) * N_SZ + r] +
                partialC[(size_t)(2 * i + 1) * N_SZ + r];
    }
    ssum -= selfexp[r];
    float v = __logf(ssum) * (1.0f / (float)N_SZ);
    if (threadIdx.x < 8) v += posbuf[blockIdx.x * 8 + threadIdx.x];
#pragma unroll
    for (int m = 32; m >= 1; m >>= 1) v += __shfl_xor(v, m, 64);
    if (threadIdx.x == 0)
        atomicAdd(out, v);
}

// ---------------------------------------------------------------------------
extern "C" void kernel_launch(void* const* d_in, const int* in_sizes, int n_in,
                              void* d_out, int out_size, void* d_ws, size_t ws_size,
                              hipStream_t stream) {
    const float* z_i = (const float*)d_in[0];
    const float* z_j = (const float*)d_in[1];
    float* out = (float*)d_out;
    char* ws = (char*)d_ws;

    unsigned int* pn = (unsigned int*)ws;                            // 2 MiB
    float* partialR = (float*)(ws + (size_t)N_SZ * D_SZ * 2);        // 256 KiB (8 x 8192)
    float* partialC = partialR + (size_t)8 * N_SZ;                   // 4 MiB (128 x 8192)
    float* selfexp = partialC + (size_t)128 * N_SZ;                  // 32 KiB
    float* posbuf = selfexp + N_SZ;                                  // 4 KiB

    norm_pos_kernel<<<B_SZ / 4, 256, 0, stream>>>(z_i, z_j, pn, posbuf,
                                                  selfexp, out);

    simexp_kernel<<<512, 128, 0, stream>>>((const char*)pn, partialR, partialC);

    lse_kernel<<<N_SZ / 64, 64, 0, stream>>>(partialR, partialC, selfexp,
                                             posbuf, out);
}

// Round 13
// 39.678 us; speedup vs baseline: 2.0815x; 2.0815x over previous
//
#include <hip/hip_runtime.h>
#include <hip/hip_bf16.h>

#define B_SZ 4096
#define N_SZ 8192
#define D_SZ 128
#define CT 8                       // 32-col tiles per strip (256 cols)
#define NSTRIP (N_SZ / (CT * 32))  // 32 col strips

constexpr float TEMP = 0.5f;
constexpr float EPS = 1e-8f;
// exp(dot/TEMP) = exp2(dot * log2(e)/TEMP); sqrt of the scale folded into
// BOTH normalized vectors so the MFMA accumulator is directly the exp2 arg.
constexpr float SQS = 1.6986436006556212f;  // sqrt(log2(e)/TEMP)

typedef short short8 __attribute__((ext_vector_type(8)));
typedef float f32x16 __attribute__((ext_vector_type(16)));

// Tiled pn layout (bf16): byte addr of element (row r, col d) =
//   (r>>5)*8192 + (d>>3)*512 + (r&31)*16 + (d&7)*2
// -> each MFMA fragment chunk is 512B contiguous across 32 lanes; a whole
//    32-row tile is one contiguous 8KB block.

// ---------------------------------------------------------------------------
// Kernel A: per wave, handle row pair (r, r+B). Normalize into tiled-bf16 pn
// (scaled by SQS); exact-f32 positive-pair term -> posbuf[block];
// selfexp[r] = exp2(self-sim of the ROUNDED bf16 row) for later diag removal.
// Block 0 thread 0 also zeroes the output accumulator.
// ---------------------------------------------------------------------------
__global__ void norm_pos_kernel(const float* __restrict__ z_i,
                                const float* __restrict__ z_j,
                                unsigned int* __restrict__ pn_u32,
                                float* __restrict__ posbuf,
                                float* __restrict__ selfexp,
                                float* __restrict__ out) {
    __shared__ float sp[4];
    int wid = threadIdx.x >> 6;
    int lane = threadIdx.x & 63;
    int r = blockIdx.x * 4 + wid;                 // [0, B)
    if (blockIdx.x == 0 && threadIdx.x == 0) out[0] = 0.0f;
    float2 vi = *reinterpret_cast<const float2*>(z_i + (size_t)r * D_SZ + lane * 2);
    float2 vj = *reinterpret_cast<const float2*>(z_j + (size_t)r * D_SZ + lane * 2);
    float ssi = vi.x * vi.x + vi.y * vi.y;
    float ssj = vj.x * vj.x + vj.y * vj.y;
    float dot = vi.x * vj.x + vi.y * vj.y;
#pragma unroll
    for (int m = 32; m >= 1; m >>= 1) {
        ssi += __shfl_xor(ssi, m, 64);
        ssj += __shfl_xor(ssj, m, 64);
        dot += __shfl_xor(dot, m, 64);
    }
    float ni = fmaxf(sqrtf(ssi), EPS);
    float nj = fmaxf(sqrtf(ssj), EPS);
    float si = SQS / ni, sj = SQS / nj;
    union { unsigned int u32; __hip_bfloat16 h[2]; } pki, pkj;
    pki.h[0] = __float2bfloat16(vi.x * si);
    pki.h[1] = __float2bfloat16(vi.y * si);
    pkj.h[0] = __float2bfloat16(vj.x * sj);
    pkj.h[1] = __float2bfloat16(vj.y * sj);
    // tiled store: lane l holds cols 2l, 2l+1 (one u32)
    int u = ((r >> 5) * 2048) + ((lane >> 2) * 128) + ((r & 31) * 4) + (lane & 3);
    pn_u32[u] = pki.u32;
    int r2 = r + B_SZ;
    int u2 = ((r2 >> 5) * 2048) + ((lane >> 2) * 128) + ((r2 & 31) * 4) + (lane & 3);
    pn_u32[u2] = pkj.u32;
    // self-similarity of the rounded rows (exp2 units, same scale as MFMA)
    float bx = __bfloat162float(pki.h[0]), by = __bfloat162float(pki.h[1]);
    float cx = __bfloat162float(pkj.h[0]), cy = __bfloat162float(pkj.h[1]);
    float sdi = bx * bx + by * by;
    float sdj = cx * cx + cy * cy;
#pragma unroll
    for (int m = 32; m >= 1; m >>= 1) {
        sdi += __shfl_xor(sdi, m, 64);
        sdj += __shfl_xor(sdj, m, 64);
    }
    if (lane == 0) {
        selfexp[r] = __builtin_amdgcn_exp2f(sdi);
        selfexp[r2] = __builtin_amdgcn_exp2f(sdj);
        sp[wid] = -dot / (ni * nj * TEMP) / (float)B_SZ;
    }
    __syncthreads();
    if (threadIdx.x == 0)
        posbuf[blockIdx.x] = sp[0] + sp[1] + sp[2] + sp[3];
}

// ---------------------------------------------------------------------------
// Kernel B (r7 structure, CN=256): partial[r][strip] = sum over the strip's
// 256 cols of exp2(sim) (diag INCLUDED — removed later via selfexp).
// Block = 2 waves x 2 row-tiles (128 rows) x 256-col strip; 2048 blocks ->
// 8 blocks/CU resident (16 waves/CU, double r7's TLP so independent blocks'
// MFMA/exp2 phases interleave across the SIMDs). Statically distinct double
// buffers bufA/bufB (no runtime indexing -> no spurious vmcnt drain).
// XCD-bijective swizzle: 2048 = 8*256; each XCD owns 4 contiguous strips.
// __launch_bounds__(128,2): (128,4) spilled in r9; VGPR ~100 measured (r8).
// C/D layout: col=lane&31, row=(reg&3)+8*(reg>>2)+4*(lane>>5).
// ---------------------------------------------------------------------------
__global__ __launch_bounds__(128, 2)
void simexp_kernel(const char* __restrict__ p, float* __restrict__ partial) {
    __shared__ char bufA[8192];
    __shared__ char bufB[8192];
    int wid = threadIdx.x >> 6;
    int lane = threadIdx.x & 63;
    int half = lane >> 5, lc = lane & 31;

    int swz = (blockIdx.x & 7) * 256 + (blockIdx.x >> 3);
    int strip = swz >> 6;          // [0,32)
    int bx = swz & 63;             // [0,64)
    int rt0 = bx * 4 + wid * 2;    // wave owns row-tiles rt0, rt0+1
    int ct0 = strip * CT;

    // A fragments: coalesced 1KB loads, held for the whole kernel
    const char* afrag = p + (size_t)rt0 * 8192 + half * 512 + lc * 16;
    short8 a0[8], a1[8];
#pragma unroll
    for (int kc = 0; kc < 8; ++kc) {
        a0[kc] = *reinterpret_cast<const short8*>(afrag + kc * 1024);
        a1[kc] = *reinterpret_cast<const short8*>(afrag + 8192 + kc * 1024);
    }

    float rs0[16], rs1[16];
#pragma unroll
    for (int i = 0; i < 16; ++i) { rs0[i] = 0.0f; rs1[i] = 0.0f; }

    // each wave stages 4 of the 8 1KB segments of one 8KB col-tile
    auto stageHalf = [&](char* buf, int ct) {
#pragma unroll
        for (int i = 0; i < 4; ++i) {
            int seg = wid * 4 + i;
            const char* g = p + (size_t)ct * 8192 + seg * 1024 + lane * 16;
            __builtin_amdgcn_global_load_lds(
                (const __attribute__((address_space(1))) unsigned int*)g,
                (__attribute__((address_space(3))) unsigned int*)(buf + seg * 1024),
                16, 0, 0);
        }
    };

    auto compute = [&](const char* buf) {
        const char* bb = buf + half * 512 + lc * 16;
        short8 b[8];
#pragma unroll
        for (int kc = 0; kc < 8; ++kc)
            b[kc] = *reinterpret_cast<const short8*>(bb + kc * 1024);
        f32x16 acc0 = {}, acc1 = {};
#pragma unroll
        for (int kc = 0; kc < 8; ++kc) {
            acc0 = __builtin_amdgcn_mfma_f32_32x32x16_bf16(a0[kc], b[kc], acc0, 0, 0, 0);
            acc1 = __builtin_amdgcn_mfma_f32_32x32x16_bf16(a1[kc], b[kc], acc1, 0, 0, 0);
        }
#pragma unroll
        for (int r = 0; r < 16; ++r) {
            rs0[r] += __builtin_amdgcn_exp2f(acc0[r]);
            rs1[r] += __builtin_amdgcn_exp2f(acc1[r]);
        }
    };

    stageHalf(bufA, ct0);
    __syncthreads();

#pragma unroll 1
    for (int t = 0; t < CT; t += 2) {
        if (t + 1 < CT) stageHalf(bufB, ct0 + t + 1);
        compute(bufA);               // reads bufA; writes went to bufB
        __syncthreads();             // drains own stage (issued ~1 phase ago)
        if (t + 2 < CT) stageHalf(bufA, ct0 + t + 2);
        compute(bufB);
        __syncthreads();
    }

    // reduce across the 32 column lanes
#pragma unroll
    for (int m = 1; m <= 16; m <<= 1) {
#pragma unroll
        for (int r = 0; r < 16; ++r) {
            rs0[r] += __shfl_xor(rs0[r], m, 64);
            rs1[r] += __shfl_xor(rs1[r], m, 64);
        }
    }
    if (lc == 0) {
#pragma unroll
        for (int r = 0; r < 16; ++r) {
            int lrow = (r & 3) + 8 * (r >> 2) + 4 * half;
            partial[(size_t)(rt0 * 32 + lrow) * NSTRIP + strip] = rs0[r];
            partial[(size_t)((rt0 + 1) * 32 + lrow) * NSTRIP + strip] = rs1[r];
        }
    }
}

// ---------------------------------------------------------------------------
// Kernel C: loss = sum(log(rowsum - selfexp))/2B + pos partials.
// 128 blocks x 64 threads; partial is [row][strip] -> 128B contiguous/thread.
// ---------------------------------------------------------------------------
__global__ void lse_kernel(const float* __restrict__ partial,
                           const float* __restrict__ selfexp,
                           const float* __restrict__ posbuf,
                           float* __restrict__ out) {
    int r = blockIdx.x * 64 + threadIdx.x;
    const float4* pr = reinterpret_cast<const float4*>(partial + (size_t)r * NSTRIP);
    float s = 0.0f;
#pragma unroll
    for (int q = 0; q < NSTRIP / 4; ++q) {
        float4 v4 = pr[q];
        s += (v4.x + v4.y) + (v4.z + v4.w);
    }
    s -= selfexp[r];
    float v = __logf(s) * (1.0f / (float)N_SZ);
    if (threadIdx.x < 8) v += posbuf[blockIdx.x * 8 + threadIdx.x];
#pragma unroll
    for (int m = 32; m >= 1; m >>= 1) v += __shfl_xor(v, m, 64);
    if (threadIdx.x == 0)
        atomicAdd(out, v);
}

// ---------------------------------------------------------------------------
extern "C" void kernel_launch(void* const* d_in, const int* in_sizes, int n_in,
                              void* d_out, int out_size, void* d_ws, size_t ws_size,
                              hipStream_t stream) {
    const float* z_i = (const float*)d_in[0];
    const float* z_j = (const float*)d_in[1];
    float* out = (float*)d_out;
    char* ws = (char*)d_ws;

    unsigned int* pn = (unsigned int*)ws;                            // 2 MiB
    float* partial = (float*)(ws + (size_t)N_SZ * D_SZ * 2);         // 1 MiB (8192 x 32)
    float* selfexp = partial + (size_t)NSTRIP * N_SZ;                // 32 KiB
    float* posbuf = selfexp + N_SZ;                                  // 4 KiB

    norm_pos_kernel<<<B_SZ / 4, 256, 0, stream>>>(z_i, z_j, pn, posbuf,
                                                  selfexp, out);

    simexp_kernel<<<2048, 128, 0, stream>>>((const char*)pn, partial);

    lse_kernel<<<N_SZ / 64, 64, 0, stream>>>(partial, selfexp, posbuf, out);
}